// Round 9
// baseline (259.416 us; speedup 1.0000x reference)
//
#include <hip/hip_runtime.h>

#define HH 32      // hidden size
#define NB 16      // batches per block (full MFMA N-tile)
#define NT 512     // 8 waves; wave w owns gate-tile w for BOTH layers
#define TT 512     // max T staged in LDS

typedef float f32x4 __attribute__((ext_vector_type(4)));
typedef __bf16 bf16x8 __attribute__((ext_vector_type(8)));
typedef unsigned int u32;
typedef unsigned short u16;
typedef u32 u32x4 __attribute__((ext_vector_type(4)));

#if __has_builtin(__builtin_amdgcn_exp2f)
#define EXP2F(x) __builtin_amdgcn_exp2f(x)
#else
#define EXP2F(x) exp2f(x)
#endif
#if __has_builtin(__builtin_amdgcn_rcpf)
#define RCPF(x) __builtin_amdgcn_rcpf(x)
#else
#define RCPF(x) (1.0f / (x))
#endif

#define S_SIGM (-1.44269504f)   // -log2(e)
#define S_TANH (-2.88539008f)   // -2*log2(e)

// A = weight fragment, B = state fragment
static __device__ __forceinline__ f32x4 mfma16(bf16x8 a, bf16x8 b, f32x4 c) {
  return __builtin_amdgcn_mfma_f32_16x16x32_bf16(a, b, c, 0, 0, 0);
}

// round-to-nearest-even f32 -> bf16 bits in TOP 16, rest zeroed
static __device__ __forceinline__ u32 rne_hi(u32 b) {
  return (b + 0x7FFFu + ((b >> 16) & 1u)) & 0xFFFF0000u;
}
static __device__ __forceinline__ u32 pack_hi16(u32 a, u32 b) {
  // result = [b[31:16] : a[31:16]]  (low u16 = a's bf16)
#if __has_builtin(__builtin_amdgcn_perm)
  return __builtin_amdgcn_perm(a, b, 0x03020706u);
#else
  return (b & 0xFFFF0000u) | (a >> 16);
#endif
}
// packed (hi|lo) bf16 pair of f32 h: low u16 = RNE(h), high u16 = bf16(h - RNE(h))
static __device__ __forceinline__ u32 pack_hl(float h) {
  const u32 b = __builtin_bit_cast(u32, h);
  const u32 r = rne_hi(b);
  const float lo = h - __builtin_bit_cast(float, r);
  return pack_hi16(r, __builtin_bit_cast(u32, lo));
}

// Packed-K weight A-frag: K-slot s (=8*kappa+e) of half `half` carries unit
// j = 16*half + (s>>1); both slots 2j,2j+1 get the SAME bf16 weight (so one
// MFMA computes sum_j W[g,j]*(h_hi[j]+h_lo[j])). Rows m: gate q=m&3, unit
// offset m>>2 within tile; pre-scaled by -log2e / -2log2e.
static __device__ __forceinline__ bf16x8 load_wfrag_ph(const float* __restrict__ M,
                                                       int tile, int half, int lane) {
  const int m = lane & 15;
  const int q = m & 3;
  const int gi = q * HH + 4 * tile + (m >> 2);
  const int kappa = lane >> 4;
  const float s = (q == 2) ? S_TANH : S_SIGM;
  const float* p = M + gi * HH + 16 * half + 4 * kappa;
  u32x4 hw;
#pragma unroll
  for (int i = 0; i < 4; ++i) {
    const float v = p[i] * s;
    const u32 w16 = rne_hi(__builtin_bit_cast(u32, v)) >> 16;
    hw[i] = w16 | (w16 << 16);          // duplicated bf16 pair (slots 2j, 2j+1)
  }
  return __builtin_bit_cast(bf16x8, hw);
}

__global__ void __launch_bounds__(NT)
lstm_fused_v9(const float* __restrict__ x,
              const float* __restrict__ W1, const float* __restrict__ b1,
              const float* __restrict__ Wih0, const float* __restrict__ Whh0,
              const float* __restrict__ bih0, const float* __restrict__ bhh0,
              const float* __restrict__ Wih1, const float* __restrict__ Whh1,
              const float* __restrict__ bih1, const float* __restrict__ bhh1,
              const float* __restrict__ W2, const float* __restrict__ b2,
              float* __restrict__ out, int T)
{
  // packed state fragments: [parity][K-half][256 u32]; u32 slot for (b, u):
  //   half = u>>4, slot = ((u&15)>>2)*64 + b*4 + (u&3)
  __shared__ __align__(16) u32 h0P[2][2][256];
  __shared__ __align__(16) u32 h1P[2][2][256];
  __shared__ __align__(16) u32 hxP[2][2][256];
  __shared__ __align__(16) float xT[TT * NB];   // x transposed [t][b], 32 KB

  const int tid  = threadIdx.x;
  const int lane = tid & 63;
  const int w    = tid >> 6;           // wave id == gate tile (0..7)
  const int G    = lane >> 4;
  const int b    = lane & 15;
  const int b0   = blockIdx.x * NB;

  // ---- weights: both layers, tile w, packed-K halves (8 bf16x8 total) ----
  const bf16x8 wr00 = load_wfrag_ph(Whh0, w, 0, lane);
  const bf16x8 wr01 = load_wfrag_ph(Whh0, w, 1, lane);
  const bf16x8 wi00 = load_wfrag_ph(Wih0, w, 0, lane);
  const bf16x8 wi01 = load_wfrag_ph(Wih0, w, 1, lane);
  const bf16x8 wr10 = load_wfrag_ph(Whh1, w, 0, lane);
  const bf16x8 wr11 = load_wfrag_ph(Whh1, w, 1, lane);
  const bf16x8 wi10 = load_wfrag_ph(Wih1, w, 0, lane);
  const bf16x8 wi11 = load_wfrag_ph(Wih1, w, 1, lane);

  const int uu = 4 * w + G;            // owned unit (0..31)
  f32x4 bias0, bias1;
#pragma unroll
  for (int q = 0; q < 4; ++q) {
    const float s = (q == 2) ? S_TANH : S_SIGM;
    bias0[q] = (bih0[q * HH + uu] + bhh0[q * HH + uu]) * s;
    bias1[q] = (bih1[q * HH + uu] + bhh1[q * HH + uu]) * s;
  }

  const int half = uu >> 4;                               // = w>>2
  const int slot = ((uu & 15) >> 2) * 64 + b * 4 + (uu & 3);  // (w&3)*64+4b+G
  const int frd  = lane * 8;           // u16 offset of this lane's 16B frag read

  const float W1u = W1[uu], b1u = b1[uu];
  const float W2a = W2[uu], W2b = W2[HH + uu];
  const f32x4 fzero = {0.f, 0.f, 0.f, 0.f};

  // ---- stage x transposed into LDS ----
  {
    const int row   = tid & 15;
    const int cbase = (tid >> 4) * 16;
    if (cbase + 16 <= T) {
      const float* xp = x + (size_t)(b0 + row) * T + cbase;
#pragma unroll
      for (int j = 0; j < 16; j += 4) {
        const float4 v = *(const float4*)(xp + j);
        xT[(cbase + j + 0) * NB + row] = v.x;
        xT[(cbase + j + 1) * NB + row] = v.y;
        xT[(cbase + j + 2) * NB + row] = v.z;
        xT[(cbase + j + 3) * NB + row] = v.w;
      }
    }
  }
  // zero-init packed state buffers: 3 arrays x 1024 u32
  ((u32*)h0P)[tid] = 0; ((u32*)h0P)[tid + 512] = 0;
  ((u32*)h1P)[tid] = 0; ((u32*)h1P)[tid + 512] = 0;
  ((u32*)hxP)[tid] = 0; ((u32*)hxP)[tid + 512] = 0;
  __syncthreads();

  // hin(0): one slot per lane
  {
    const float xv = xT[b];
    hxP[0][half][slot] = pack_hl(fmaxf(__builtin_fmaf(xv, W1u, b1u), 0.0f));
  }
  float c0 = 0.0f, c1 = 0.0f, h0v = 0.0f, h1v = 0.0f;
  __syncthreads();

#define GATES(z, c, h) {                                                \
    const float ei = EXP2F(z[0]), ef = EXP2F(z[1]);                     \
    const float eg = EXP2F(z[2]), eo = EXP2F(z[3]);                     \
    const float iv = RCPF(1.0f + ei), fv = RCPF(1.0f + ef);             \
    const float gv = __builtin_fmaf(2.0f, RCPF(1.0f + eg), -1.0f);      \
    const float ov = RCPF(1.0f + eo);                                   \
    c = __builtin_fmaf(fv, c, iv * gv);                                 \
    h = ov * __builtin_fmaf(2.0f, RCPF(1.0f + EXP2F(c * S_TANH)), -1.0f); \
  }

// iter k: every wave does L0(t=k) AND L1(t=k-1) (independent chains) + hin(k+1).
// ONE barrier. S-frags (h0[RB]) are shared by both chains. L1 runs as two
// independent 2-MFMA chains + add (shorter dependency than a 4-chain).
#define STEP(kk, WB, DO_L0, DO_L1, DO_HIN)                               \
  {                                                                      \
    const int RB = (WB) ^ 1;                                             \
    const bf16x8 S0 = *(const bf16x8*)((const u16*)h0P[RB][0] + frd);    \
    const bf16x8 S1 = *(const bf16x8*)((const u16*)h0P[RB][1] + frd);    \
    if (DO_L0) {                                                         \
      const bf16x8 P0 = *(const bf16x8*)((const u16*)hxP[WB][0] + frd);  \
      const bf16x8 P1 = *(const bf16x8*)((const u16*)hxP[WB][1] + frd);  \
      f32x4 z0 = mfma16(wi01, P1, bias0);                                \
      z0 = mfma16(wi00, P0, z0);                                         \
      z0 = mfma16(wr01, S1, z0);                                         \
      z0 = mfma16(wr00, S0, z0);                                         \
      if (DO_HIN) {                                                      \
        const float xv = xT[((kk) + 1) * NB + b];                        \
        hxP[RB][half][slot] =                                            \
            pack_hl(fmaxf(__builtin_fmaf(xv, W1u, b1u), 0.0f));          \
      }                                                                  \
      GATES(z0, c0, h0v);                                                \
      h0P[WB][half][slot] = pack_hl(h0v);                                \
    }                                                                    \
    if (DO_L1) {                                                         \
      const bf16x8 T0 = *(const bf16x8*)((const u16*)h1P[WB][0] + frd);  \
      const bf16x8 T1 = *(const bf16x8*)((const u16*)h1P[WB][1] + frd);  \
      f32x4 z1a = mfma16(wi10, S0, bias1);                               \
      f32x4 z1b = mfma16(wr10, T0, fzero);                               \
      z1a = mfma16(wi11, S1, z1a);                                       \
      z1b = mfma16(wr11, T1, z1b);                                       \
      const f32x4 z1 = z1a + z1b;                                        \
      GATES(z1, c1, h1v);                                                \
      h1P[RB][half][slot] = pack_hl(h1v);                                \
    }                                                                    \
    __syncthreads();                                                     \
  }

  STEP(0, 0, true, false, true);                  // k=0: L0 only + hin(1)
  for (int kk = 1; kk + 1 < T; kk += 2) {         // k = 1..T-2 in parity pairs
    STEP(kk, 1, true, true, true);
    STEP(kk + 1, 0, true, true, true);
  }
  STEP(T - 1, 1, true, true, false);              // k=T-1 (odd): no hin(T)
  STEP(T, 0, false, true, false);                 // k=T: L1 only

#undef STEP
#undef GATES

  // ---- epilogue: out[b] = sum_u h0f[b,u]*W2[u] + h1f[b,u]*W2[H+u] + b2 ----
  xT[uu * NB + b] = __builtin_fmaf(h0v, W2a, h1v * W2b);   // [32][16], unique slots
  __syncthreads();
  if (tid < NB) {
    float acc = b2[0];
#pragma unroll
    for (int u = 0; u < HH; ++u) acc += xT[u * NB + tid];
    out[b0 + tid] = acc;
  }
}

extern "C" void kernel_launch(void* const* d_in, const int* in_sizes, int n_in,
                              void* d_out, int out_size, void* d_ws, size_t ws_size,
                              hipStream_t stream) {
  const float* x    = (const float*)d_in[0];
  const float* W1   = (const float*)d_in[1];
  const float* b1   = (const float*)d_in[2];
  const float* Wih0 = (const float*)d_in[3];
  const float* Whh0 = (const float*)d_in[4];
  const float* bih0 = (const float*)d_in[5];
  const float* bhh0 = (const float*)d_in[6];
  const float* Wih1 = (const float*)d_in[7];
  const float* Whh1 = (const float*)d_in[8];
  const float* bih1 = (const float*)d_in[9];
  const float* bhh1 = (const float*)d_in[10];
  const float* W2   = (const float*)d_in[11];
  const float* b2   = (const float*)d_in[12];

  const int B = out_size;                 // 4096
  const int I = in_sizes[1] / HH;         // 1
  const int T = in_sizes[0] / (B * I);    // 512
  const int blocks = B / NB;              // 256 -> 1 block/CU

  lstm_fused_v9<<<blocks, NT, 0, stream>>>(
      x, W1, b1, Wih0, Whh0, bih0, bhh0, Wih1, Whh1, bih1, bhh1, W2, b2,
      (float*)d_out, T);
}

// Round 10
// 228.313 us; speedup vs baseline: 1.1362x; 1.1362x over previous
//
#include <hip/hip_runtime.h>

#define HH 32      // hidden size
#define NB 16      // batches per block (full MFMA N-tile)
#define NT 512     // 8 waves; wave w owns gate-tile w for BOTH layers
#define TT 512     // max T staged in LDS

typedef float f32x4 __attribute__((ext_vector_type(4)));
typedef __bf16 bf16x8 __attribute__((ext_vector_type(8)));
typedef unsigned int u32;
typedef unsigned short u16;
typedef u32 u32x4 __attribute__((ext_vector_type(4)));

#if __has_builtin(__builtin_amdgcn_exp2f)
#define EXP2F(x) __builtin_amdgcn_exp2f(x)
#else
#define EXP2F(x) exp2f(x)
#endif
#if __has_builtin(__builtin_amdgcn_rcpf)
#define RCPF(x) __builtin_amdgcn_rcpf(x)
#else
#define RCPF(x) (1.0f / (x))
#endif

#define S_SIGM (-1.44269504f)   // -log2(e)
#define S_TANH (-2.88539008f)   // -2*log2(e)

// A = weight fragment, B = state fragment
static __device__ __forceinline__ f32x4 mfma16(bf16x8 a, bf16x8 b, f32x4 c) {
  return __builtin_amdgcn_mfma_f32_16x16x32_bf16(a, b, c, 0, 0, 0);
}

// round-to-nearest-even f32 -> bf16 bits in TOP 16, rest zeroed
static __device__ __forceinline__ u32 rne_hi(u32 b) {
  return (b + 0x7FFFu + ((b >> 16) & 1u)) & 0xFFFF0000u;
}
static __device__ __forceinline__ u32 pack_hi16(u32 a, u32 b) {
  // result = [b[31:16] : a[31:16]]  (low u16 = a's bf16)
#if __has_builtin(__builtin_amdgcn_perm)
  return __builtin_amdgcn_perm(a, b, 0x03020706u);
#else
  return (b & 0xFFFF0000u) | (a >> 16);
#endif
}
// packed (hi|lo) bf16 pair of f32 h: low u16 = RNE(h), high u16 = bf16(h - RNE(h))
static __device__ __forceinline__ u32 pack_hl(float h) {
  const u32 b = __builtin_bit_cast(u32, h);
  const u32 r = rne_hi(b);
  const float lo = h - __builtin_bit_cast(float, r);
  return pack_hi16(r, __builtin_bit_cast(u32, lo));
}

// Packed-K weight A-frag: K-slot s (=8*kappa+e) of half `half` carries unit
// j = 16*half + (s>>1); both slots 2j,2j+1 get the SAME bf16 weight (so one
// MFMA computes sum_j W[g,j]*(h_hi[j]+h_lo[j])). Rows m: gate q=m&3, unit
// offset m>>2 within tile; pre-scaled by -log2e / -2log2e.
static __device__ __forceinline__ bf16x8 load_wfrag_ph(const float* __restrict__ M,
                                                       int tile, int half, int lane) {
  const int m = lane & 15;
  const int q = m & 3;
  const int gi = q * HH + 4 * tile + (m >> 2);
  const int kappa = lane >> 4;
  const float s = (q == 2) ? S_TANH : S_SIGM;
  const float* p = M + gi * HH + 16 * half + 4 * kappa;
  u32x4 hw;
#pragma unroll
  for (int i = 0; i < 4; ++i) {
    const float v = p[i] * s;
    const u32 w16 = rne_hi(__builtin_bit_cast(u32, v)) >> 16;
    hw[i] = w16 | (w16 << 16);          // duplicated bf16 pair (slots 2j, 2j+1)
  }
  return __builtin_bit_cast(bf16x8, hw);
}

__global__ void __launch_bounds__(NT)
lstm_fused_v7(const float* __restrict__ x,
              const float* __restrict__ W1, const float* __restrict__ b1,
              const float* __restrict__ Wih0, const float* __restrict__ Whh0,
              const float* __restrict__ bih0, const float* __restrict__ bhh0,
              const float* __restrict__ Wih1, const float* __restrict__ Whh1,
              const float* __restrict__ bih1, const float* __restrict__ bhh1,
              const float* __restrict__ W2, const float* __restrict__ b2,
              float* __restrict__ out, int T)
{
  // packed state fragments: [parity][K-half][256 u32]; u32 slot for (b, u):
  //   half = u>>4, slot = ((u&15)>>2)*64 + b*4 + (u&3)
  __shared__ __align__(16) u32 h0P[2][2][256];
  __shared__ __align__(16) u32 h1P[2][2][256];
  __shared__ __align__(16) u32 hxP[2][2][256];
  __shared__ __align__(16) float xT[TT * NB];   // x transposed [t][b], 32 KB

  const int tid  = threadIdx.x;
  const int lane = tid & 63;
  const int w    = tid >> 6;           // wave id == gate tile (0..7)
  const int G    = lane >> 4;
  const int b    = lane & 15;
  const int b0   = blockIdx.x * NB;

  // ---- weights: both layers, tile w, packed-K halves (8 bf16x8 total) ----
  const bf16x8 wr00 = load_wfrag_ph(Whh0, w, 0, lane);
  const bf16x8 wr01 = load_wfrag_ph(Whh0, w, 1, lane);
  const bf16x8 wi00 = load_wfrag_ph(Wih0, w, 0, lane);
  const bf16x8 wi01 = load_wfrag_ph(Wih0, w, 1, lane);
  const bf16x8 wr10 = load_wfrag_ph(Whh1, w, 0, lane);
  const bf16x8 wr11 = load_wfrag_ph(Whh1, w, 1, lane);
  const bf16x8 wi10 = load_wfrag_ph(Wih1, w, 0, lane);
  const bf16x8 wi11 = load_wfrag_ph(Wih1, w, 1, lane);

  const int uu = 4 * w + G;            // owned unit (0..31)
  f32x4 bias0, bias1;
#pragma unroll
  for (int q = 0; q < 4; ++q) {
    const float s = (q == 2) ? S_TANH : S_SIGM;
    bias0[q] = (bih0[q * HH + uu] + bhh0[q * HH + uu]) * s;
    bias1[q] = (bih1[q * HH + uu] + bhh1[q * HH + uu]) * s;
  }

  const int half = uu >> 4;                               // = w>>2
  const int slot = ((uu & 15) >> 2) * 64 + b * 4 + (uu & 3);  // (w&3)*64+4b+G
  const int frd  = lane * 8;           // u16 offset of this lane's 16B frag read

  const float W1u = W1[uu], b1u = b1[uu];
  const float W2a = W2[uu], W2b = W2[HH + uu];

  // ---- stage x transposed into LDS ----
  {
    const int row   = tid & 15;
    const int cbase = (tid >> 4) * 16;
    if (cbase + 16 <= T) {
      const float* xp = x + (size_t)(b0 + row) * T + cbase;
#pragma unroll
      for (int j = 0; j < 16; j += 4) {
        const float4 v = *(const float4*)(xp + j);
        xT[(cbase + j + 0) * NB + row] = v.x;
        xT[(cbase + j + 1) * NB + row] = v.y;
        xT[(cbase + j + 2) * NB + row] = v.z;
        xT[(cbase + j + 3) * NB + row] = v.w;
      }
    }
  }
  // zero-init packed state buffers: 3 arrays x 1024 u32
  ((u32*)h0P)[tid] = 0; ((u32*)h0P)[tid + 512] = 0;
  ((u32*)h1P)[tid] = 0; ((u32*)h1P)[tid + 512] = 0;
  ((u32*)hxP)[tid] = 0; ((u32*)hxP)[tid + 512] = 0;
  __syncthreads();

  // hin(0): one slot per lane
  {
    const float xv = xT[b];
    hxP[0][half][slot] = pack_hl(fmaxf(__builtin_fmaf(xv, W1u, b1u), 0.0f));
  }
  float c0 = 0.0f, c1 = 0.0f, h0v = 0.0f, h1v = 0.0f;
  __syncthreads();

#define GATES(z, c, h) {                                                \
    const float ei = EXP2F(z[0]), ef = EXP2F(z[1]);                     \
    const float eg = EXP2F(z[2]), eo = EXP2F(z[3]);                     \
    const float iv = RCPF(1.0f + ei), fv = RCPF(1.0f + ef);             \
    const float gv = __builtin_fmaf(2.0f, RCPF(1.0f + eg), -1.0f);      \
    const float ov = RCPF(1.0f + eo);                                   \
    c = __builtin_fmaf(fv, c, iv * gv);                                 \
    h = ov * __builtin_fmaf(2.0f, RCPF(1.0f + EXP2F(c * S_TANH)), -1.0f); \
  }

// iter k: every wave does L0(t=k) AND L1(t=k-1) (independent chains) + hin(k+1).
// ONE barrier. S-frags (h0[RB]) are shared by both chains.
#define STEP(kk, WB, DO_L0, DO_L1, DO_HIN)                               \
  {                                                                      \
    const int RB = (WB) ^ 1;                                             \
    const bf16x8 S0 = *(const bf16x8*)((const u16*)h0P[RB][0] + frd);    \
    const bf16x8 S1 = *(const bf16x8*)((const u16*)h0P[RB][1] + frd);    \
    if (DO_L0) {                                                         \
      const bf16x8 P0 = *(const bf16x8*)((const u16*)hxP[WB][0] + frd);  \
      const bf16x8 P1 = *(const bf16x8*)((const u16*)hxP[WB][1] + frd);  \
      f32x4 z0 = mfma16(wi01, P1, bias0);                                \
      z0 = mfma16(wi00, P0, z0);                                         \
      z0 = mfma16(wr01, S1, z0);                                         \
      z0 = mfma16(wr00, S0, z0);                                         \
      if (DO_HIN) {                                                      \
        const float xv = xT[((kk) + 1) * NB + b];                        \
        hxP[RB][half][slot] =                                            \
            pack_hl(fmaxf(__builtin_fmaf(xv, W1u, b1u), 0.0f));          \
      }                                                                  \
      GATES(z0, c0, h0v);                                                \
      h0P[WB][half][slot] = pack_hl(h0v);                                \
    }                                                                    \
    if (DO_L1) {                                                         \
      const bf16x8 T0 = *(const bf16x8*)((const u16*)h1P[WB][0] + frd);  \
      const bf16x8 T1 = *(const bf16x8*)((const u16*)h1P[WB][1] + frd);  \
      f32x4 z1 = mfma16(wi11, S1, bias1);                                \
      z1 = mfma16(wi10, S0, z1);                                         \
      z1 = mfma16(wr11, T1, z1);                                         \
      z1 = mfma16(wr10, T0, z1);                                         \
      GATES(z1, c1, h1v);                                                \
      h1P[RB][half][slot] = pack_hl(h1v);                                \
    }                                                                    \
    __syncthreads();                                                     \
  }

  STEP(0, 0, true, false, true);                  // k=0: L0 only + hin(1)
  for (int kk = 1; kk + 1 < T; kk += 2) {         // k = 1..T-2 in parity pairs
    STEP(kk, 1, true, true, true);
    STEP(kk + 1, 0, true, true, true);
  }
  STEP(T - 1, 1, true, true, false);              // k=T-1 (odd): no hin(T)
  STEP(T, 0, false, true, false);                 // k=T: L1 only

#undef STEP
#undef GATES

  // ---- epilogue: out[b] = sum_u h0f[b,u]*W2[u] + h1f[b,u]*W2[H+u] + b2 ----
  xT[uu * NB + b] = __builtin_fmaf(h0v, W2a, h1v * W2b);   // [32][16], unique slots
  __syncthreads();
  if (tid < NB) {
    float acc = b2[0];
#pragma unroll
    for (int u = 0; u < HH; ++u) acc += xT[u * NB + tid];
    out[b0 + tid] = acc;
  }
}

extern "C" void kernel_launch(void* const* d_in, const int* in_sizes, int n_in,
                              void* d_out, int out_size, void* d_ws, size_t ws_size,
                              hipStream_t stream) {
  const float* x    = (const float*)d_in[0];
  const float* W1   = (const float*)d_in[1];
  const float* b1   = (const float*)d_in[2];
  const float* Wih0 = (const float*)d_in[3];
  const float* Whh0 = (const float*)d_in[4];
  const float* bih0 = (const float*)d_in[5];
  const float* bhh0 = (const float*)d_in[6];
  const float* Wih1 = (const float*)d_in[7];
  const float* Whh1 = (const float*)d_in[8];
  const float* bih1 = (const float*)d_in[9];
  const float* bhh1 = (const float*)d_in[10];
  const float* W2   = (const float*)d_in[11];
  const float* b2   = (const float*)d_in[12];

  const int B = out_size;                 // 4096
  const int I = in_sizes[1] / HH;         // 1
  const int T = in_sizes[0] / (B * I);    // 512
  const int blocks = B / NB;              // 256 -> 1 block/CU

  lstm_fused_v7<<<blocks, NT, 0, stream>>>(
      x, W1, b1, Wih0, Whh0, bih0, bhh0, Wih1, Whh1, bih1, bhh1, W2, b2,
      (float*)d_out, T);
}